// Round 6
// baseline (515.162 us; speedup 1.0000x reference)
//
#include <hip/hip_runtime.h>
#include <cstdint>
#include <cstddef>

#define N_NODES 50000
#define HDIM 64
#define NREL 50
#define NEDGE 800000
#define DCHUNK 196   // ceil(N_NODES/256)
#define CPARTS 5     // count_k privatization parts (ILP factor)
#define SCH 5        // scatter_k edges per thread (1280/block; 800000%1280==0)

typedef __attribute__((ext_vector_type(8))) short short8;
typedef __attribute__((ext_vector_type(4))) float f32x4;

static __device__ __forceinline__ unsigned short f2bf(float f) {
  union { float f; unsigned int u; } v; v.f = f;
  unsigned int u = v.u;
  unsigned int r = (u + 0x7FFFu + ((u >> 16) & 1u)) >> 16;  // RNE
  return (unsigned short)r;
}

// ---- preprocessing -------------------------------------------------------

// per-dst count (5-way privatized) + per-edge rank + rel histogram.
__global__ __launch_bounds__(256) void count_k(const int* __restrict__ ei,
                                               const int* __restrict__ et,
                                               int* __restrict__ dcnt5,
                                               int* __restrict__ hist,
                                               int* __restrict__ rank) {
  __shared__ int lh[NREL];
  int tid = threadIdx.x;
  if (tid < NREL) lh[tid] = 0;
  __syncthreads();
  int ebase = blockIdx.x * (256 * CPARTS) + tid;
  int rk[CPARTS];
#pragma unroll
  for (int i = 0; i < CPARTS; ++i) {
    int e = ebase + i * 256;                    // NEDGE % 1280 == 0, no guard
    int r = et[e];
    int dst = ei[NEDGE + e];
    rk[i] = atomicAdd(&dcnt5[i * N_NODES + dst], 1);
    atomicAdd(&lh[r], 1);
  }
#pragma unroll
  for (int i = 0; i < CPARTS; ++i)
    rank[ebase + i * 256] = rk[i];
  __syncthreads();
  if (tid < NREL && lh[tid] > 0) atomicAdd(&hist[tid], lh[tid]);
}

// fold 5 sub-counters: pref[p][dst] = sum_{q<p} dcnt5[q][dst]; dcnt = total
__global__ void pref_k(const int* __restrict__ dcnt5, int* __restrict__ pref,
                       int* __restrict__ dcnt) {
  int idx = blockIdx.x * 256 + threadIdx.x;
  if (idx >= N_NODES) return;
  int acc = 0;
#pragma unroll
  for (int p = 0; p < CPARTS; ++p) {
    pref[p * N_NODES + idx] = acc;
    acc += dcnt5[p * N_NODES + idx];
  }
  dcnt[idx] = acc;
}

// 1-wave shuffle scan of the 50-entry relation histogram
__global__ void relscan_k(const int* __restrict__ hist, int* __restrict__ rel_off,
                          int* __restrict__ cursor) {
  int l = threadIdx.x;                          // 64 threads
  int v = (l < NREL) ? hist[l] : 0;
  int incl = v;
#pragma unroll
  for (int off = 1; off < 64; off <<= 1) {
    int u = __shfl_up(incl, off, 64);
    if (l >= off) incl += u;
  }
  if (l < NREL) { rel_off[l + 1] = incl; cursor[l] = incl - v; }
  if (l == 0) rel_off[0] = 0;
}

// dst_off scan, 3-phase multi-block
__global__ __launch_bounds__(256) void dsA_k(const int* __restrict__ dcnt,
                                             int* __restrict__ psum) {
  __shared__ int red[256];
  int t = threadIdx.x, b = blockIdx.x;
  int idx = b * DCHUNK + t;
  int v = (t < DCHUNK && idx < N_NODES) ? dcnt[idx] : 0;
  red[t] = v;
  __syncthreads();
  for (int s = 128; s > 0; s >>= 1) {
    if (t < s) red[t] += red[t + s];
    __syncthreads();
  }
  if (t == 0) psum[b] = red[0];
}

__global__ __launch_bounds__(256) void dsB_k(const int* __restrict__ psum,
                                             int* __restrict__ psb,
                                             int* __restrict__ dst_off) {
  __shared__ int a[256], bb[256];
  int t = threadIdx.x;
  int v = psum[t];
  a[t] = v;
  __syncthreads();
  bool flip = false;
  for (int off = 1; off < 256; off <<= 1) {
    int* c = flip ? bb : a;
    int* n = flip ? a : bb;
    int x = c[t];
    if (t >= off) x += c[t - off];
    n[t] = x;
    __syncthreads();
    flip = !flip;
  }
  int incl = (flip ? bb : a)[t];
  psb[t] = incl - v;
  if (t == 255) dst_off[N_NODES] = incl;
}

__global__ __launch_bounds__(256) void dsC_k(const int* __restrict__ dcnt,
                                             const int* __restrict__ psb,
                                             int* __restrict__ dst_off) {
  __shared__ int a[256], bb[256];
  int t = threadIdx.x, b = blockIdx.x;
  int idx = b * DCHUNK + t;
  int v = (t < DCHUNK && idx < N_NODES) ? dcnt[idx] : 0;
  a[t] = v;
  __syncthreads();
  bool flip = false;
  for (int off = 1; off < 256; off <<= 1) {
    int* c = flip ? bb : a;
    int* n = flip ? a : bb;
    int x = c[t];
    if (t >= off) x += c[t - off];
    n[t] = x;
    __syncthreads();
    flip = !flip;
  }
  int incl = (flip ? bb : a)[t];
  if (t < DCHUNK && idx < N_NODES) dst_off[idx] = psb[b] + (incl - v);
}

// rel counting-sort scatter, 1280 edges/block. Packs (src,dp) into int2 so
// rel-sorted writes land in ~205B runs; only rpos remains a random 4B scatter.
__global__ __launch_bounds__(256) void scatter_k(const int* __restrict__ ei,
                                                 const int* __restrict__ et,
                                                 const int* __restrict__ rank,
                                                 const int* __restrict__ dst_off,
                                                 const int* __restrict__ pref,
                                                 int* __restrict__ cursor,
                                                 int2* __restrict__ esd,
                                                 int* __restrict__ rpos) {
  __shared__ int lh[NREL];
  __shared__ int lb[NREL];
  int tid = threadIdx.x;
  if (tid < NREL) lh[tid] = 0;
  __syncthreads();
  int ebase = blockIdx.x * (256 * SCH) + tid;
  int r_[SCH], loc_[SCH], src_[SCH], dp_[SCH];
#pragma unroll
  for (int i = 0; i < SCH; ++i) {
    int e = ebase + i * 256;                    // NEDGE % 1280 == 0
    int r = et[e];
    int dst = ei[NEDGE + e];
    int part = (e % (256 * CPARTS)) >> 8;       // = i here (SCH==CPARTS)
    r_[i] = r;
    src_[i] = ei[e];
    dp_[i] = dst_off[dst] + pref[part * N_NODES + dst] + rank[e];
    loc_[i] = atomicAdd(&lh[r], 1);             // LDS
  }
  __syncthreads();
  if (tid < NREL) lb[tid] = (lh[tid] > 0) ? atomicAdd(&cursor[tid], lh[tid]) : 0;
  __syncthreads();
#pragma unroll
  for (int i = 0; i < SCH; ++i) {
    int pos = lb[r_[i]] + loc_[i];              // rel-sorted slot
    esd[pos] = make_int2(src_[i], dp_[i]);
    rpos[dp_[i]] = r_[i];
  }
}

// per-dst: coefd[j] = 1 / #(edges in j's dst-segment with same rel)
__global__ void coef_k(const int* __restrict__ rpos, const int* __restrict__ dst_off,
                       float* __restrict__ coefd) {
  int dst = blockIdx.x * 256 + threadIdx.x;
  if (dst >= N_NODES) return;
  int lo = dst_off[dst], hi = dst_off[dst + 1];
  for (int j = lo; j < hi; ++j) {
    int r = rpos[j];
    int c = 0;
    for (int k = lo; k < hi; ++k) c += (rpos[k] == r);
    coefd[j] = 1.0f / (float)c;
  }
}

// weight prep: transpose to [r][o][d] bf16; expand block-diagonal to dense
__global__ void prep_k(const float* __restrict__ w0, const float* __restrict__ w1,
                       const float* __restrict__ w2,
                       const float* __restrict__ wr0f, const float* __restrict__ wr1f,
                       const float* __restrict__ wr2f,
                       unsigned short* __restrict__ Wt0, unsigned short* __restrict__ Wt1,
                       unsigned short* __restrict__ Wt2,
                       unsigned short* __restrict__ Wr0, unsigned short* __restrict__ Wr1,
                       unsigned short* __restrict__ Wr2) {
  int idx = blockIdx.x * 256 + threadIdx.x;
  if (idx < NREL * 4096) {
    int r = idx >> 12, rem = idx & 4095, d = rem >> 6, o = rem & 63;
    int tpos = (r << 12) + (o << 6) + d;        // [r][o][d]
    Wt2[tpos] = f2bf(w2[idx]);                  // w2 is [r][d][o]
    int b = o >> 4;
    float v0 = 0.f, v1 = 0.f;
    if (b == (d >> 4)) {
      int widx = ((r * 4 + b) * 16 + (d & 15)) * 16 + (o & 15);
      v0 = w0[widx];
      v1 = w1[widx];
    }
    Wt0[tpos] = f2bf(v0);
    Wt1[tpos] = f2bf(v1);
  }
  if (idx < 4096) {
    int d = idx >> 6, o = idx & 63;
    int tpos = (o << 6) + d;
    Wr0[tpos] = f2bf(wr0f[idx]);
    Wr1[tpos] = f2bf(wr1f[idx]);
    Wr2[tpos] = f2bf(wr2f[idx]);
  }
}

// fp32 -> bf16 convert (layer-0 input only)
__global__ void conv_k(const float* __restrict__ in, unsigned short* __restrict__ out) {
  int i = blockIdx.x * 256 + threadIdx.x;
  out[i] = f2bf(in[i]);
}

// ---- per-layer kernels ---------------------------------------------------
// MFMA 16x16x32 bf16. A-frag: m=lane&15, k=quad*8+j (16B chunk of a row).
// B-frag: n=lane&15, k=quad*8+j, contiguous in Wt[o][d].
// C/D: col=lane&15, row=quad*4+i.

// h[n,:] = bias + x[n,:] @ w_root
__global__ __launch_bounds__(256) void root_k(const unsigned short* __restrict__ xbf,
                                              const unsigned short* __restrict__ wr,
                                              const float* __restrict__ bias,
                                              float* __restrict__ out) {
  int wid = threadIdx.x >> 6, lane = threadIdx.x & 63;
  int n15 = lane & 15, quad = lane >> 4;
  int t = blockIdx.x * 4 + wid;
  if (t >= N_NODES / 16) return;
  short8 bfr[4][2];
#pragma unroll
  for (int nb = 0; nb < 4; ++nb)
#pragma unroll
    for (int k = 0; k < 2; ++k)
      bfr[nb][k] = *reinterpret_cast<const short8*>(wr + ((nb * 16 + n15) << 6) + k * 32 + quad * 8);
  float bv[4];
#pragma unroll
  for (int nb = 0; nb < 4; ++nb) bv[nb] = bias[nb * 16 + n15];

  int base = t * 16;
  const short8* xr = reinterpret_cast<const short8*>(xbf + (size_t)(base + n15) * 64);
  short8 a0 = xr[quad], a1 = xr[4 + quad];
  f32x4 acc[4];
#pragma unroll
  for (int nb = 0; nb < 4; ++nb) acc[nb] = (f32x4){0.f, 0.f, 0.f, 0.f};
#pragma unroll
  for (int nb = 0; nb < 4; ++nb) {
    acc[nb] = __builtin_amdgcn_mfma_f32_16x16x32_bf16(a0, bfr[nb][0], acc[nb], 0, 0, 0);
    acc[nb] = __builtin_amdgcn_mfma_f32_16x16x32_bf16(a1, bfr[nb][1], acc[nb], 0, 0, 0);
  }
#pragma unroll
  for (int i = 0; i < 4; ++i) {
    int node = base + quad * 4 + i;
#pragma unroll
    for (int nb = 0; nb < 4; ++nb)
      out[(size_t)node * 64 + nb * 16 + n15] = acc[nb][i] + bv[nb];
  }
}

// msg[dp(e),:] = x[src_e,:] @ W_rel   (unscaled; agg applies coef)
__global__ __launch_bounds__(256) void edge_k(const unsigned short* __restrict__ xbf,
                                              const unsigned short* __restrict__ wt,
                                              const int2* __restrict__ esd,
                                              const int* __restrict__ rel_off,
                                              unsigned short* __restrict__ msg) {
  int r = blockIdx.y;
  int lo = rel_off[r], hi = rel_off[r + 1];
  if (lo >= hi) return;
  int wid = threadIdx.x >> 6, lane = threadIdx.x & 63;
  int n15 = lane & 15, quad = lane >> 4;
  const unsigned short* wr = wt + ((size_t)r << 12);
  short8 bfr[4][2];
#pragma unroll
  for (int nb = 0; nb < 4; ++nb)
#pragma unroll
    for (int k = 0; k < 2; ++k)
      bfr[nb][k] = *reinterpret_cast<const short8*>(wr + ((nb * 16 + n15) << 6) + k * 32 + quad * 8);

  int ntiles = (hi - lo + 15) >> 4;
  for (int t = blockIdx.x * 4 + wid; t < ntiles; t += gridDim.x * 4) {
    int base = lo + t * 16;
    int eidx = base + n15;
    if (eidx > NEDGE - 1) eidx = NEDGE - 1;     // safe read; epilogue guards validity
    int src = esd[eidx].x;
    const short8* xr = reinterpret_cast<const short8*>(xbf + (size_t)src * 64);
    short8 a0 = xr[quad], a1 = xr[4 + quad];
    f32x4 acc[4];
#pragma unroll
    for (int nb = 0; nb < 4; ++nb) acc[nb] = (f32x4){0.f, 0.f, 0.f, 0.f};
#pragma unroll
    for (int nb = 0; nb < 4; ++nb) {
      acc[nb] = __builtin_amdgcn_mfma_f32_16x16x32_bf16(a0, bfr[nb][0], acc[nb], 0, 0, 0);
      acc[nb] = __builtin_amdgcn_mfma_f32_16x16x32_bf16(a1, bfr[nb][1], acc[nb], 0, 0, 0);
    }
#pragma unroll
    for (int i = 0; i < 4; ++i) {
      int e2 = base + quad * 4 + i;
      if (e2 < hi) {
        size_t row = (size_t)esd[e2].y * 64;
#pragma unroll
        for (int nb = 0; nb < 4; ++nb)
          msg[row + nb * 16 + n15] = f2bf(acc[nb][i]);
      }
    }
  }
}

// out[dst,:] = h[dst,:] + sum coefd[e]*msg[e,:]; mode 0: relu+bf16, mode 1: fp32
__global__ __launch_bounds__(256) void agg_k(const float* __restrict__ h,
                                             const unsigned short* __restrict__ msg,
                                             const float* __restrict__ coefd,
                                             const int* __restrict__ dst_off,
                                             float* __restrict__ outf,
                                             unsigned short* __restrict__ outbf,
                                             int mode) {
  int lane = threadIdx.x & 63;
  int wv = (blockIdx.x * 256 + threadIdx.x) >> 6;
  int half = lane >> 5, l = lane & 31;
  int dst = wv * 2 + half;
  if (dst >= N_NODES) return;
  int lo = dst_off[dst], hi = dst_off[dst + 1];
  float ax = h[(size_t)dst * 64 + 2 * l];
  float ay = h[(size_t)dst * 64 + 2 * l + 1];
  for (int e = lo; e < hi; ++e) {
    float c = coefd[e];
    unsigned int u = *reinterpret_cast<const unsigned int*>(msg + (size_t)e * 64 + 2 * l);
    union { unsigned int u; float f; } cx, cy;
    cx.u = (u & 0xFFFFu) << 16;
    cy.u = u & 0xFFFF0000u;
    ax += c * cx.f;
    ay += c * cy.f;
  }
  if (mode == 0) {
    float fx = fmaxf(ax, 0.f), fy = fmaxf(ay, 0.f);
    unsigned int pk = ((unsigned int)f2bf(fy) << 16) | (unsigned int)f2bf(fx);
    *reinterpret_cast<unsigned int*>(outbf + (size_t)dst * 64 + 2 * l) = pk;
  } else {
    float2 o2; o2.x = ax; o2.y = ay;
    *reinterpret_cast<float2*>(outf + (size_t)dst * 64 + 2 * l) = o2;
  }
}

// ---- launcher ------------------------------------------------------------

extern "C" void kernel_launch(void* const* d_in, const int* in_sizes, int n_in,
                              void* d_out, int out_size, void* d_ws, size_t ws_size,
                              hipStream_t stream) {
  const float* x   = (const float*)d_in[0];
  const int*   ei  = (const int*)d_in[1];
  const int*   et  = (const int*)d_in[2];
  const float* w0  = (const float*)d_in[3];
  const float* wr0 = (const float*)d_in[4];
  const float* b0  = (const float*)d_in[5];
  const float* w1  = (const float*)d_in[6];
  const float* wr1 = (const float*)d_in[7];
  const float* b1  = (const float*)d_in[8];
  const float* w2  = (const float*)d_in[9];
  const float* wr2 = (const float*)d_in[10];
  const float* b2  = (const float*)d_in[11];
  float* out = (float*)d_out;

  char* p = (char*)d_ws;
  auto take = [&](size_t bytes) -> char* {
    char* q = p;
    p += (bytes + 255) & ~(size_t)255;
    return q;
  };
  int*   hist    = (int*)take(NREL * 4);
  int*   cursor  = (int*)take(NREL * 4);
  int*   rel_off = (int*)take((NREL + 1) * 4);
  int*   dcnt5   = (int*)take((size_t)CPARTS * N_NODES * 4);
  int*   pref    = (int*)take((size_t)CPARTS * N_NODES * 4);
  int*   dcnt    = (int*)take((size_t)N_NODES * 4);
  int*   dst_off = (int*)take((size_t)(N_NODES + 1) * 4);
  int*   psum    = (int*)take(256 * 4);
  int*   psb     = (int*)take(256 * 4);
  int*   rank    = (int*)take((size_t)NEDGE * 4);
  int2*  esd     = (int2*)take((size_t)NEDGE * 8);
  int*   rpos    = (int*)take((size_t)NEDGE * 4);
  float* coefd   = (float*)take((size_t)NEDGE * 4);
  unsigned short* xbf = (unsigned short*)take((size_t)N_NODES * 64 * 2);
  float* h       = (float*)take((size_t)N_NODES * 64 * 4);
  unsigned short* msg = (unsigned short*)take((size_t)NEDGE * 64 * 2);  // 102.4 MB
  unsigned short* Wt0 = (unsigned short*)take((size_t)NREL * 4096 * 2);
  unsigned short* Wt1 = (unsigned short*)take((size_t)NREL * 4096 * 2);
  unsigned short* Wt2 = (unsigned short*)take((size_t)NREL * 4096 * 2);
  unsigned short* Wr0 = (unsigned short*)take(4096 * 2);
  unsigned short* Wr1 = (unsigned short*)take(4096 * 2);
  unsigned short* Wr2 = (unsigned short*)take(4096 * 2);

  // preprocessing (edge structure shared by all 3 layers)
  hipMemsetAsync(hist, 0, NREL * 4, stream);
  hipMemsetAsync(dcnt5, 0, (size_t)CPARTS * N_NODES * 4, stream);
  count_k<<<NEDGE / (256 * CPARTS), 256, 0, stream>>>(ei, et, dcnt5, hist, rank);
  pref_k<<<(N_NODES + 255) / 256, 256, 0, stream>>>(dcnt5, pref, dcnt);
  relscan_k<<<1, 64, 0, stream>>>(hist, rel_off, cursor);
  dsA_k<<<256, 256, 0, stream>>>(dcnt, psum);
  dsB_k<<<1, 256, 0, stream>>>(psum, psb, dst_off);
  dsC_k<<<256, 256, 0, stream>>>(dcnt, psb, dst_off);
  scatter_k<<<NEDGE / (256 * SCH), 256, 0, stream>>>(ei, et, rank, dst_off, pref,
                                                     cursor, esd, rpos);
  coef_k<<<(N_NODES + 255) / 256, 256, 0, stream>>>(rpos, dst_off, coefd);
  prep_k<<<(NREL * 4096 + 255) / 256, 256, 0, stream>>>(w0, w1, w2, wr0, wr1, wr2,
                                                        Wt0, Wt1, Wt2, Wr0, Wr1, Wr2);

  const int conv_blocks = N_NODES * 64 / 256;      // 12500, exact
  const int root_blocks = (N_NODES / 16 + 3) / 4;  // 782
  const int agg_blocks  = N_NODES / 8;             // 6250: 4 waves/block x 2 dst/wave
  dim3 eg(80, NREL);

  // layer 0
  conv_k<<<conv_blocks, 256, 0, stream>>>(x, xbf);
  root_k<<<root_blocks, 256, 0, stream>>>(xbf, Wr0, b0, h);
  edge_k<<<eg, 256, 0, stream>>>(xbf, Wt0, esd, rel_off, msg);
  agg_k<<<agg_blocks, 256, 0, stream>>>(h, msg, coefd, dst_off, nullptr, xbf, 0);
  // layer 1
  root_k<<<root_blocks, 256, 0, stream>>>(xbf, Wr1, b1, h);
  edge_k<<<eg, 256, 0, stream>>>(xbf, Wt1, esd, rel_off, msg);
  agg_k<<<agg_blocks, 256, 0, stream>>>(h, msg, coefd, dst_off, nullptr, xbf, 0);
  // layer 2 (no ReLU, fp32 out)
  root_k<<<root_blocks, 256, 0, stream>>>(xbf, Wr2, b2, h);
  edge_k<<<eg, 256, 0, stream>>>(xbf, Wt2, esd, rel_off, msg);
  agg_k<<<agg_blocks, 256, 0, stream>>>(h, msg, coefd, dst_off, out, nullptr, 1);
}

// Round 7
// 459.682 us; speedup vs baseline: 1.1207x; 1.1207x over previous
//
#include <hip/hip_runtime.h>
#include <cstdint>
#include <cstddef>

#define N_NODES 50000
#define HDIM 64
#define NREL 50
#define NEDGE 800000
#define DCHUNK 196   // ceil(N_NODES/256)
#define CPARTS 5     // count_k privatization parts (ILP factor)
#define SCH 5        // scatter_k edges per thread (1280/block; 800000%1280==0)

typedef __attribute__((ext_vector_type(8))) short short8;
typedef __attribute__((ext_vector_type(4))) float f32x4;

static __device__ __forceinline__ unsigned short f2bf(float f) {
  union { float f; unsigned int u; } v; v.f = f;
  unsigned int u = v.u;
  unsigned int r = (u + 0x7FFFu + ((u >> 16) & 1u)) >> 16;  // RNE
  return (unsigned short)r;
}

// ---- preprocessing -------------------------------------------------------

// per-dst count (5-way privatized) + per-edge rank + rel histogram.
__global__ __launch_bounds__(256) void count_k(const int* __restrict__ ei,
                                               const int* __restrict__ et,
                                               int* __restrict__ dcnt5,
                                               int* __restrict__ hist,
                                               int* __restrict__ rank) {
  __shared__ int lh[NREL];
  int tid = threadIdx.x;
  if (tid < NREL) lh[tid] = 0;
  __syncthreads();
  int ebase = blockIdx.x * (256 * CPARTS) + tid;
  int rk[CPARTS];
#pragma unroll
  for (int i = 0; i < CPARTS; ++i) {
    int e = ebase + i * 256;                    // NEDGE % 1280 == 0, no guard
    int r = et[e];
    int dst = ei[NEDGE + e];
    rk[i] = atomicAdd(&dcnt5[i * N_NODES + dst], 1);
    atomicAdd(&lh[r], 1);
  }
#pragma unroll
  for (int i = 0; i < CPARTS; ++i)
    rank[ebase + i * 256] = rk[i];
  __syncthreads();
  if (tid < NREL && lh[tid] > 0) atomicAdd(&hist[tid], lh[tid]);
}

// fold 5 sub-counters: pref[p][dst] = sum_{q<p} dcnt5[q][dst]; dcnt = total
__global__ void pref_k(const int* __restrict__ dcnt5, int* __restrict__ pref,
                       int* __restrict__ dcnt) {
  int idx = blockIdx.x * 256 + threadIdx.x;
  if (idx >= N_NODES) return;
  int acc = 0;
#pragma unroll
  for (int p = 0; p < CPARTS; ++p) {
    pref[p * N_NODES + idx] = acc;
    acc += dcnt5[p * N_NODES + idx];
  }
  dcnt[idx] = acc;
}

// 1-wave shuffle scan of the 50-entry relation histogram
__global__ void relscan_k(const int* __restrict__ hist, int* __restrict__ rel_off,
                          int* __restrict__ cursor) {
  int l = threadIdx.x;                          // 64 threads
  int v = (l < NREL) ? hist[l] : 0;
  int incl = v;
#pragma unroll
  for (int off = 1; off < 64; off <<= 1) {
    int u = __shfl_up(incl, off, 64);
    if (l >= off) incl += u;
  }
  if (l < NREL) { rel_off[l + 1] = incl; cursor[l] = incl - v; }
  if (l == 0) rel_off[0] = 0;
}

// dst_off scan, 3-phase multi-block
__global__ __launch_bounds__(256) void dsA_k(const int* __restrict__ dcnt,
                                             int* __restrict__ psum) {
  __shared__ int red[256];
  int t = threadIdx.x, b = blockIdx.x;
  int idx = b * DCHUNK + t;
  int v = (t < DCHUNK && idx < N_NODES) ? dcnt[idx] : 0;
  red[t] = v;
  __syncthreads();
  for (int s = 128; s > 0; s >>= 1) {
    if (t < s) red[t] += red[t + s];
    __syncthreads();
  }
  if (t == 0) psum[b] = red[0];
}

__global__ __launch_bounds__(256) void dsB_k(const int* __restrict__ psum,
                                             int* __restrict__ psb,
                                             int* __restrict__ dst_off) {
  __shared__ int a[256], bb[256];
  int t = threadIdx.x;
  int v = psum[t];
  a[t] = v;
  __syncthreads();
  bool flip = false;
  for (int off = 1; off < 256; off <<= 1) {
    int* c = flip ? bb : a;
    int* n = flip ? a : bb;
    int x = c[t];
    if (t >= off) x += c[t - off];
    n[t] = x;
    __syncthreads();
    flip = !flip;
  }
  int incl = (flip ? bb : a)[t];
  psb[t] = incl - v;
  if (t == 255) dst_off[N_NODES] = incl;
}

__global__ __launch_bounds__(256) void dsC_k(const int* __restrict__ dcnt,
                                             const int* __restrict__ psb,
                                             int* __restrict__ dst_off) {
  __shared__ int a[256], bb[256];
  int t = threadIdx.x, b = blockIdx.x;
  int idx = b * DCHUNK + t;
  int v = (t < DCHUNK && idx < N_NODES) ? dcnt[idx] : 0;
  a[t] = v;
  __syncthreads();
  bool flip = false;
  for (int off = 1; off < 256; off <<= 1) {
    int* c = flip ? bb : a;
    int* n = flip ? a : bb;
    int x = c[t];
    if (t >= off) x += c[t - off];
    n[t] = x;
    __syncthreads();
    flip = !flip;
  }
  int incl = (flip ? bb : a)[t];
  if (t < DCHUNK && idx < N_NODES) dst_off[idx] = psb[b] + (incl - v);
}

// rel counting-sort scatter, 1280 edges/block. Packs (src,dp) into int2 so
// rel-sorted writes land in ~205B runs; only rpos remains a random 4B scatter.
__global__ __launch_bounds__(256) void scatter_k(const int* __restrict__ ei,
                                                 const int* __restrict__ et,
                                                 const int* __restrict__ rank,
                                                 const int* __restrict__ dst_off,
                                                 const int* __restrict__ pref,
                                                 int* __restrict__ cursor,
                                                 int2* __restrict__ esd,
                                                 int* __restrict__ rpos) {
  __shared__ int lh[NREL];
  __shared__ int lb[NREL];
  int tid = threadIdx.x;
  if (tid < NREL) lh[tid] = 0;
  __syncthreads();
  int ebase = blockIdx.x * (256 * SCH) + tid;
  int r_[SCH], loc_[SCH], src_[SCH], dp_[SCH];
#pragma unroll
  for (int i = 0; i < SCH; ++i) {
    int e = ebase + i * 256;                    // NEDGE % 1280 == 0
    int r = et[e];
    int dst = ei[NEDGE + e];
    int part = (e % (256 * CPARTS)) >> 8;       // = i here (SCH==CPARTS)
    r_[i] = r;
    src_[i] = ei[e];
    dp_[i] = dst_off[dst] + pref[part * N_NODES + dst] + rank[e];
    loc_[i] = atomicAdd(&lh[r], 1);             // LDS
  }
  __syncthreads();
  if (tid < NREL) lb[tid] = (lh[tid] > 0) ? atomicAdd(&cursor[tid], lh[tid]) : 0;
  __syncthreads();
#pragma unroll
  for (int i = 0; i < SCH; ++i) {
    int pos = lb[r_[i]] + loc_[i];              // rel-sorted slot
    esd[pos] = make_int2(src_[i], dp_[i]);
    rpos[dp_[i]] = r_[i];
  }
}

// coefd[j] = 1 / #(edges in j's dst-segment with same rel).
// One half-wave per dst (agg_k decomposition): lane l handles elements
// lo+l, lo+l+32, ...; inner rpos scan is wave-uniform (broadcast loads).
__global__ __launch_bounds__(256) void coef_k(const int* __restrict__ rpos,
                                              const int* __restrict__ dst_off,
                                              float* __restrict__ coefd) {
  int lane = threadIdx.x & 63;
  int wv = (blockIdx.x * 256 + threadIdx.x) >> 6;
  int half = lane >> 5, l = lane & 31;
  int dst = wv * 2 + half;
  if (dst >= N_NODES) return;
  int lo = dst_off[dst], hi = dst_off[dst + 1];
  for (int j = lo + l; j < hi; j += 32) {
    int r = rpos[j];
    int c = 0;
    for (int k = lo; k < hi; ++k) c += (rpos[k] == r);
    coefd[j] = 1.0f / (float)c;
  }
}

// weight prep: transpose to [r][o][d] bf16; expand block-diagonal to dense
__global__ void prep_k(const float* __restrict__ w0, const float* __restrict__ w1,
                       const float* __restrict__ w2,
                       const float* __restrict__ wr0f, const float* __restrict__ wr1f,
                       const float* __restrict__ wr2f,
                       unsigned short* __restrict__ Wt0, unsigned short* __restrict__ Wt1,
                       unsigned short* __restrict__ Wt2,
                       unsigned short* __restrict__ Wr0, unsigned short* __restrict__ Wr1,
                       unsigned short* __restrict__ Wr2) {
  int idx = blockIdx.x * 256 + threadIdx.x;
  if (idx < NREL * 4096) {
    int r = idx >> 12, rem = idx & 4095, d = rem >> 6, o = rem & 63;
    int tpos = (r << 12) + (o << 6) + d;        // [r][o][d]
    Wt2[tpos] = f2bf(w2[idx]);                  // w2 is [r][d][o]
    int b = o >> 4;
    float v0 = 0.f, v1 = 0.f;
    if (b == (d >> 4)) {
      int widx = ((r * 4 + b) * 16 + (d & 15)) * 16 + (o & 15);
      v0 = w0[widx];
      v1 = w1[widx];
    }
    Wt0[tpos] = f2bf(v0);
    Wt1[tpos] = f2bf(v1);
  }
  if (idx < 4096) {
    int d = idx >> 6, o = idx & 63;
    int tpos = (o << 6) + d;
    Wr0[tpos] = f2bf(wr0f[idx]);
    Wr1[tpos] = f2bf(wr1f[idx]);
    Wr2[tpos] = f2bf(wr2f[idx]);
  }
}

// fp32 -> bf16 convert (layer-0 input only)
__global__ void conv_k(const float* __restrict__ in, unsigned short* __restrict__ out) {
  int i = blockIdx.x * 256 + threadIdx.x;
  out[i] = f2bf(in[i]);
}

// ---- per-layer kernels ---------------------------------------------------
// MFMA 16x16x32 bf16. A-frag: m=lane&15, k=quad*8+j (16B chunk of a row).
// B-frag: n=lane&15, k=quad*8+j, contiguous in Wt[o][d].
// C/D: col=lane&15, row=quad*4+i.

// h[n,:] = bias + x[n,:] @ w_root
__global__ __launch_bounds__(256) void root_k(const unsigned short* __restrict__ xbf,
                                              const unsigned short* __restrict__ wr,
                                              const float* __restrict__ bias,
                                              float* __restrict__ out) {
  int wid = threadIdx.x >> 6, lane = threadIdx.x & 63;
  int n15 = lane & 15, quad = lane >> 4;
  int t = blockIdx.x * 4 + wid;
  if (t >= N_NODES / 16) return;
  short8 bfr[4][2];
#pragma unroll
  for (int nb = 0; nb < 4; ++nb)
#pragma unroll
    for (int k = 0; k < 2; ++k)
      bfr[nb][k] = *reinterpret_cast<const short8*>(wr + ((nb * 16 + n15) << 6) + k * 32 + quad * 8);
  float bv[4];
#pragma unroll
  for (int nb = 0; nb < 4; ++nb) bv[nb] = bias[nb * 16 + n15];

  int base = t * 16;
  const short8* xr = reinterpret_cast<const short8*>(xbf + (size_t)(base + n15) * 64);
  short8 a0 = xr[quad], a1 = xr[4 + quad];
  f32x4 acc[4];
#pragma unroll
  for (int nb = 0; nb < 4; ++nb) acc[nb] = (f32x4){0.f, 0.f, 0.f, 0.f};
#pragma unroll
  for (int nb = 0; nb < 4; ++nb) {
    acc[nb] = __builtin_amdgcn_mfma_f32_16x16x32_bf16(a0, bfr[nb][0], acc[nb], 0, 0, 0);
    acc[nb] = __builtin_amdgcn_mfma_f32_16x16x32_bf16(a1, bfr[nb][1], acc[nb], 0, 0, 0);
  }
#pragma unroll
  for (int i = 0; i < 4; ++i) {
    int node = base + quad * 4 + i;
#pragma unroll
    for (int nb = 0; nb < 4; ++nb)
      out[(size_t)node * 64 + nb * 16 + n15] = acc[nb][i] + bv[nb];
  }
}

// msg[dp(e),:] = x[src_e,:] @ W_rel   (unscaled; agg applies coef)
__global__ __launch_bounds__(256) void edge_k(const unsigned short* __restrict__ xbf,
                                              const unsigned short* __restrict__ wt,
                                              const int2* __restrict__ esd,
                                              const int* __restrict__ rel_off,
                                              unsigned short* __restrict__ msg) {
  int r = blockIdx.y;
  int lo = rel_off[r], hi = rel_off[r + 1];
  if (lo >= hi) return;
  int wid = threadIdx.x >> 6, lane = threadIdx.x & 63;
  int n15 = lane & 15, quad = lane >> 4;
  const unsigned short* wr = wt + ((size_t)r << 12);
  short8 bfr[4][2];
#pragma unroll
  for (int nb = 0; nb < 4; ++nb)
#pragma unroll
    for (int k = 0; k < 2; ++k)
      bfr[nb][k] = *reinterpret_cast<const short8*>(wr + ((nb * 16 + n15) << 6) + k * 32 + quad * 8);

  int ntiles = (hi - lo + 15) >> 4;
  for (int t = blockIdx.x * 4 + wid; t < ntiles; t += gridDim.x * 4) {
    int base = lo + t * 16;
    int eidx = base + n15;
    if (eidx > NEDGE - 1) eidx = NEDGE - 1;     // safe read; epilogue guards validity
    int src = esd[eidx].x;
    const short8* xr = reinterpret_cast<const short8*>(xbf + (size_t)src * 64);
    short8 a0 = xr[quad], a1 = xr[4 + quad];
    f32x4 acc[4];
#pragma unroll
    for (int nb = 0; nb < 4; ++nb) acc[nb] = (f32x4){0.f, 0.f, 0.f, 0.f};
#pragma unroll
    for (int nb = 0; nb < 4; ++nb) {
      acc[nb] = __builtin_amdgcn_mfma_f32_16x16x32_bf16(a0, bfr[nb][0], acc[nb], 0, 0, 0);
      acc[nb] = __builtin_amdgcn_mfma_f32_16x16x32_bf16(a1, bfr[nb][1], acc[nb], 0, 0, 0);
    }
#pragma unroll
    for (int i = 0; i < 4; ++i) {
      int e2 = base + quad * 4 + i;
      if (e2 < hi) {
        size_t row = (size_t)esd[e2].y * 64;
#pragma unroll
        for (int nb = 0; nb < 4; ++nb)
          msg[row + nb * 16 + n15] = f2bf(acc[nb][i]);
      }
    }
  }
}

// out[dst,:] = h[dst,:] + sum coefd[e]*msg[e,:]; mode 0: relu+bf16, mode 1: fp32
__global__ __launch_bounds__(256) void agg_k(const float* __restrict__ h,
                                             const unsigned short* __restrict__ msg,
                                             const float* __restrict__ coefd,
                                             const int* __restrict__ dst_off,
                                             float* __restrict__ outf,
                                             unsigned short* __restrict__ outbf,
                                             int mode) {
  int lane = threadIdx.x & 63;
  int wv = (blockIdx.x * 256 + threadIdx.x) >> 6;
  int half = lane >> 5, l = lane & 31;
  int dst = wv * 2 + half;
  if (dst >= N_NODES) return;
  int lo = dst_off[dst], hi = dst_off[dst + 1];
  float ax = h[(size_t)dst * 64 + 2 * l];
  float ay = h[(size_t)dst * 64 + 2 * l + 1];
  for (int e = lo; e < hi; ++e) {
    float c = coefd[e];
    unsigned int u = *reinterpret_cast<const unsigned int*>(msg + (size_t)e * 64 + 2 * l);
    union { unsigned int u; float f; } cx, cy;
    cx.u = (u & 0xFFFFu) << 16;
    cy.u = u & 0xFFFF0000u;
    ax += c * cx.f;
    ay += c * cy.f;
  }
  if (mode == 0) {
    float fx = fmaxf(ax, 0.f), fy = fmaxf(ay, 0.f);
    unsigned int pk = ((unsigned int)f2bf(fy) << 16) | (unsigned int)f2bf(fx);
    *reinterpret_cast<unsigned int*>(outbf + (size_t)dst * 64 + 2 * l) = pk;
  } else {
    float2 o2; o2.x = ax; o2.y = ay;
    *reinterpret_cast<float2*>(outf + (size_t)dst * 64 + 2 * l) = o2;
  }
}

// ---- launcher ------------------------------------------------------------

extern "C" void kernel_launch(void* const* d_in, const int* in_sizes, int n_in,
                              void* d_out, int out_size, void* d_ws, size_t ws_size,
                              hipStream_t stream) {
  const float* x   = (const float*)d_in[0];
  const int*   ei  = (const int*)d_in[1];
  const int*   et  = (const int*)d_in[2];
  const float* w0  = (const float*)d_in[3];
  const float* wr0 = (const float*)d_in[4];
  const float* b0  = (const float*)d_in[5];
  const float* w1  = (const float*)d_in[6];
  const float* wr1 = (const float*)d_in[7];
  const float* b1  = (const float*)d_in[8];
  const float* w2  = (const float*)d_in[9];
  const float* wr2 = (const float*)d_in[10];
  const float* b2  = (const float*)d_in[11];
  float* out = (float*)d_out;

  char* p = (char*)d_ws;
  auto take = [&](size_t bytes) -> char* {
    char* q = p;
    p += (bytes + 255) & ~(size_t)255;
    return q;
  };
  int*   hist    = (int*)take(NREL * 4);
  int*   cursor  = (int*)take(NREL * 4);
  int*   rel_off = (int*)take((NREL + 1) * 4);
  int*   dcnt5   = (int*)take((size_t)CPARTS * N_NODES * 4);
  int*   pref    = (int*)take((size_t)CPARTS * N_NODES * 4);
  int*   dcnt    = (int*)take((size_t)N_NODES * 4);
  int*   dst_off = (int*)take((size_t)(N_NODES + 1) * 4);
  int*   psum    = (int*)take(256 * 4);
  int*   psb     = (int*)take(256 * 4);
  int*   rank    = (int*)take((size_t)NEDGE * 4);
  int2*  esd     = (int2*)take((size_t)NEDGE * 8);
  int*   rpos    = (int*)take((size_t)NEDGE * 4);
  float* coefd   = (float*)take((size_t)NEDGE * 4);
  unsigned short* xbf = (unsigned short*)take((size_t)N_NODES * 64 * 2);
  float* h       = (float*)take((size_t)N_NODES * 64 * 4);
  unsigned short* msg = (unsigned short*)take((size_t)NEDGE * 64 * 2);  // 102.4 MB
  unsigned short* Wt0 = (unsigned short*)take((size_t)NREL * 4096 * 2);
  unsigned short* Wt1 = (unsigned short*)take((size_t)NREL * 4096 * 2);
  unsigned short* Wt2 = (unsigned short*)take((size_t)NREL * 4096 * 2);
  unsigned short* Wr0 = (unsigned short*)take(4096 * 2);
  unsigned short* Wr1 = (unsigned short*)take(4096 * 2);
  unsigned short* Wr2 = (unsigned short*)take(4096 * 2);

  // preprocessing (edge structure shared by all 3 layers)
  hipMemsetAsync(hist, 0, NREL * 4, stream);
  hipMemsetAsync(dcnt5, 0, (size_t)CPARTS * N_NODES * 4, stream);
  count_k<<<NEDGE / (256 * CPARTS), 256, 0, stream>>>(ei, et, dcnt5, hist, rank);
  pref_k<<<(N_NODES + 255) / 256, 256, 0, stream>>>(dcnt5, pref, dcnt);
  relscan_k<<<1, 64, 0, stream>>>(hist, rel_off, cursor);
  dsA_k<<<256, 256, 0, stream>>>(dcnt, psum);
  dsB_k<<<1, 256, 0, stream>>>(psum, psb, dst_off);
  dsC_k<<<256, 256, 0, stream>>>(dcnt, psb, dst_off);
  scatter_k<<<NEDGE / (256 * SCH), 256, 0, stream>>>(ei, et, rank, dst_off, pref,
                                                     cursor, esd, rpos);
  coef_k<<<N_NODES / 8, 256, 0, stream>>>(rpos, dst_off, coefd);
  prep_k<<<(NREL * 4096 + 255) / 256, 256, 0, stream>>>(w0, w1, w2, wr0, wr1, wr2,
                                                        Wt0, Wt1, Wt2, Wr0, Wr1, Wr2);

  const int conv_blocks = N_NODES * 64 / 256;      // 12500, exact
  const int root_blocks = (N_NODES / 16 + 3) / 4;  // 782
  const int agg_blocks  = N_NODES / 8;             // 6250: 4 waves/block x 2 dst/wave
  dim3 eg(80, NREL);

  // layer 0
  conv_k<<<conv_blocks, 256, 0, stream>>>(x, xbf);
  root_k<<<root_blocks, 256, 0, stream>>>(xbf, Wr0, b0, h);
  edge_k<<<eg, 256, 0, stream>>>(xbf, Wt0, esd, rel_off, msg);
  agg_k<<<agg_blocks, 256, 0, stream>>>(h, msg, coefd, dst_off, nullptr, xbf, 0);
  // layer 1
  root_k<<<root_blocks, 256, 0, stream>>>(xbf, Wr1, b1, h);
  edge_k<<<eg, 256, 0, stream>>>(xbf, Wt1, esd, rel_off, msg);
  agg_k<<<agg_blocks, 256, 0, stream>>>(h, msg, coefd, dst_off, nullptr, xbf, 0);
  // layer 2 (no ReLU, fp32 out)
  root_k<<<root_blocks, 256, 0, stream>>>(xbf, Wr2, b2, h);
  edge_k<<<eg, 256, 0, stream>>>(xbf, Wt2, esd, rel_off, msg);
  agg_k<<<agg_blocks, 256, 0, stream>>>(h, msg, coefd, dst_off, out, nullptr, 1);
}